// Round 6
// baseline (1400.707 us; speedup 1.0000x reference)
//
#include <hip/hip_runtime.h>

#define EPSV 1e-5f
#define CDIV(a, b) (((a) + (b) - 1) / (b))

using short8 = __attribute__((ext_vector_type(8))) short;
using f32x4 = __attribute__((ext_vector_type(4))) float;

__device__ __forceinline__ unsigned short bf16rne(float x) {
  unsigned u = __float_as_uint(x);
  unsigned r = (u + 0x7fffu + ((u >> 16) & 1u)) >> 16;
  return (unsigned short)r;
}

// ---------------- stage 0: seg_mean(pf, p2v_in) ----------------
__global__ void k_scatter_in(const float* __restrict__ pf, const int* __restrict__ p2v,
                             float* __restrict__ vf0, int total) {
  int i = blockIdx.x * 256 + threadIdx.x;
  if (i >= total) return;
  atomicAdd(&vf0[(size_t)p2v[i >> 5] * 32 + (i & 31)], pf[i]);
}

__global__ void k_div_in(float* __restrict__ vf0, const float* __restrict__ cnt, int total) {
  int i = blockIdx.x * 256 + threadIdx.x;
  if (i >= total) return;
  vf0[i] /= cnt[i >> 5];
}

// ---------------- conv1: 8-tap, 32->64, fp32 VALU, + BN stats ----------------
__global__ __launch_bounds__(256) void k_conv1(const float* __restrict__ vin,
                                               const int* __restrict__ cmap,
                                               const float* __restrict__ W,  // [8][32][64]
                                               float* __restrict__ out,
                                               float* __restrict__ stats, int Vout) {
  __shared__ float fs[32][128];
  __shared__ float Ws[32 * 64];
  __shared__ int idxs[128 * 8];
  __shared__ float ss[128];
  const int tid = threadIdx.x;
  const int vb = blockIdx.x * 128;
  for (int i = tid; i < 128 * 8; i += 256) {
    int g = vb * 8 + i;
    idxs[i] = (g < Vout * 8) ? cmap[g] : -1;
  }
  if (tid < 128) ss[tid] = 0.f;
  const int vq = tid & 15, cq = tid >> 4;
  const int v0 = vq * 8, c0 = cq * 4;
  const int srow = tid & 127, sci = (tid >> 7) * 16;
  float acc[8][4];
#pragma unroll
  for (int r = 0; r < 8; ++r)
#pragma unroll
    for (int q = 0; q < 4; ++q) acc[r][q] = 0.f;

  for (int k = 0; k < 8; ++k) {
    __syncthreads();
    for (int i = tid; i < 32 * 64; i += 256) Ws[i] = W[k * 2048 + i];
    int idx = idxs[srow * 8 + k];
    if (idx >= 0) {
#pragma unroll
      for (int j = 0; j < 16; j += 4) {
        float4 t = *(const float4*)&vin[(size_t)idx * 32 + sci + j];
        fs[sci + j + 0][srow] = t.x;
        fs[sci + j + 1][srow] = t.y;
        fs[sci + j + 2][srow] = t.z;
        fs[sci + j + 3][srow] = t.w;
      }
    } else {
#pragma unroll
      for (int j = 0; j < 16; ++j) fs[sci + j][srow] = 0.f;
    }
    __syncthreads();
#pragma unroll 8
    for (int ci = 0; ci < 32; ++ci) {
      float4 w4 = *(const float4*)&Ws[ci * 64 + c0];
      float4 fa = *(const float4*)&fs[ci][v0];
      float4 fb = *(const float4*)&fs[ci][v0 + 4];
      float fv[8] = {fa.x, fa.y, fa.z, fa.w, fb.x, fb.y, fb.z, fb.w};
      float wv[4] = {w4.x, w4.y, w4.z, w4.w};
#pragma unroll
      for (int r = 0; r < 8; ++r)
#pragma unroll
        for (int q = 0; q < 4; ++q) acc[r][q] += fv[r] * wv[q];
    }
  }
  float s1[4] = {0, 0, 0, 0}, s2[4] = {0, 0, 0, 0};
#pragma unroll
  for (int r = 0; r < 8; ++r) {
    int v = vb + v0 + r;
    if (v < Vout) {
      *(float4*)&out[(size_t)v * 64 + c0] =
          make_float4(acc[r][0], acc[r][1], acc[r][2], acc[r][3]);
#pragma unroll
      for (int q = 0; q < 4; ++q) {
        float x = acc[r][q];
        s1[q] += x;
        s2[q] += x * x;
      }
    }
  }
#pragma unroll
  for (int q = 0; q < 4; ++q) {
    atomicAdd(&ss[c0 + q], s1[q]);
    atomicAdd(&ss[64 + c0 + q], s2[q]);
  }
  __syncthreads();
  if (tid < 128) atomicAdd(&stats[tid], ss[tid]);
}

// ---------------- BN finalize ----------------
__global__ void k_bnfin(const float* __restrict__ stats, const float* __restrict__ g,
                        const float* __restrict__ b, float* __restrict__ sb, int rows) {
  int c = threadIdx.x;
  float inv = 1.f / (float)rows;
  float m = stats[c] * inv;
  float v = stats[64 + c] * inv - m * m;
  float sc = g[c] * rsqrtf(v + EPSV);
  sb[c] = sc;
  sb[64 + c] = b[c] - m * sc;
}

// ---------------- counting sort: voxel -> point list ----------------
__global__ __launch_bounds__(1024) void k_scan_part(const float* __restrict__ cnt,
                                                    int* __restrict__ partial, int V) {
  __shared__ int s[1024];
  int i = blockIdx.x * 1024 + threadIdx.x;
  s[threadIdx.x] = (i < V) ? (int)cnt[i] : 0;
  __syncthreads();
  for (int st = 512; st > 0; st >>= 1) {
    if (threadIdx.x < st) s[threadIdx.x] += s[threadIdx.x + st];
    __syncthreads();
  }
  if (threadIdx.x == 0) partial[blockIdx.x] = s[0];
}

__global__ __launch_bounds__(1024) void k_scan_top(int* __restrict__ partial, int nb) {
  __shared__ int s[1024];
  int t = threadIdx.x;
  int orig = (t < nb) ? partial[t] : 0;
  s[t] = orig;
  __syncthreads();
  for (int st = 1; st < 1024; st <<= 1) {
    int v = (t >= st) ? s[t - st] : 0;
    __syncthreads();
    s[t] += v;
    __syncthreads();
  }
  if (t < nb) partial[t] = s[t] - orig;  // exclusive
}

__global__ __launch_bounds__(1024) void k_scan_write(const float* __restrict__ cnt,
                                                     const int* __restrict__ partial,
                                                     int* __restrict__ starts,
                                                     int* __restrict__ cursor, int V) {
  __shared__ int s[1024];
  int t = threadIdx.x;
  int i = blockIdx.x * 1024 + t;
  int orig = (i < V) ? (int)cnt[i] : 0;
  s[t] = orig;
  __syncthreads();
  for (int st = 1; st < 1024; st <<= 1) {
    int v = (t >= st) ? s[t - st] : 0;
    __syncthreads();
    s[t] += v;
    __syncthreads();
  }
  if (i < V) {
    int excl = s[t] - orig + partial[blockIdx.x];
    starts[i] = excl;
    cursor[i] = excl;
  }
}

__global__ void k_bucket(const int* __restrict__ p2v, int* __restrict__ cursor,
                         int* __restrict__ plist, int N) {
  int p = blockIdx.x * 256 + threadIdx.x;
  if (p >= N) return;
  int pos = atomicAdd(&cursor[p2v[p]], 1);
  plist[pos] = p;
}

// ---------------- tri1 fused with seg_mean: per-voxel corner gather ----------------
__global__ __launch_bounds__(256) void k_tri1v(const float* __restrict__ c1,
                                               const float* __restrict__ sb0,
                                               const int* __restrict__ tidx,
                                               const float* __restrict__ twt,
                                               const int* __restrict__ starts,
                                               const float* __restrict__ cnt,
                                               const int* __restrict__ plist,
                                               float* __restrict__ pfeat,
                                               float* __restrict__ vf2, int V) {
  int t = threadIdx.x;
  int v = blockIdx.x * 4 + (t >> 6);
  int c = t & 63;
  if (v >= V) return;
  int s0 = starts[v];
  int n = (int)cnt[v];
  if (n < 1) return;
  int p0 = plist[s0];
  float sc = sb0[c], bi = sb0[64 + c];
  float R[8];
#pragma unroll
  for (int j = 0; j < 8; ++j) {
    int idx = tidx[(size_t)p0 * 8 + j];
    R[j] = (idx >= 0) ? fmaxf(sc * c1[(size_t)idx * 64 + c] + bi, 0.f) : 0.f;
  }
  float acc_v = 0.f;
  for (int i = 0; i < n; ++i) {
    int p = plist[s0 + i];
    float4 w0 = *(const float4*)&twt[(size_t)p * 8];
    float4 w1 = *(const float4*)&twt[(size_t)p * 8 + 4];
    float acc = w0.x * R[0] + w0.y * R[1] + w0.z * R[2] + w0.w * R[3] +
                w1.x * R[4] + w1.y * R[5] + w1.z * R[6] + w1.w * R[7];
    pfeat[(size_t)p * 64 + c] = acc;
    acc_v += acc;
  }
  vf2[(size_t)v * 64 + c] = acc_v / (float)n;
}

// ---------------- weight prep: W[k][ci][co] f32 -> fragment-linear bf16 hi/lo ----------------
__global__ void k_wprep(const float* __restrict__ W, short* __restrict__ Wh,
                        short* __restrict__ Wl, int ntap) {
  int t = blockIdx.x * 256 + threadIdx.x;
  int total = ntap * 2 * 4 * 64;
  if (t >= total) return;
  int l = t & 63;
  int n = (t >> 6) & 3;
  int s = (t >> 8) & 1;
  int k = t >> 9;
  int co = n * 16 + (l & 15);
  int ci0 = s * 32 + (l >> 4) * 8;
#pragma unroll
  for (int j = 0; j < 8; ++j) {
    float x = W[((size_t)(k * 64 + ci0 + j)) * 64 + co];
    unsigned short hb = bf16rne(x);
    float hf = __uint_as_float((unsigned)hb << 16);
    Wh[(size_t)t * 8 + j] = (short)hb;
    Wl[(size_t)t * 8 + j] = (short)bf16rne(x - hf);
  }
}

// ---------------- split: fp32 -> bf16 hi/lo, optional fused BN+ReLU ----------------
__global__ void k_split(const float* __restrict__ in, const float* __restrict__ sb,
                        short* __restrict__ oh, short* __restrict__ ol, int total) {
  int i = blockIdx.x * 256 + threadIdx.x;
  if (i >= total) return;
  float x = in[i];
  if (sb) {
    int c = i & 63;
    x = fmaxf(sb[c] * x + sb[64 + c], 0.f);
  }
  unsigned short hb = bf16rne(x);
  float hf = __uint_as_float((unsigned)hb << 16);
  oh[i] = (short)hb;
  ol[i] = (short)bf16rne(x - hf);
}

// ---------------- conv27 via MFMA, BM=128, linear LDS, reg-pipelined idx ----------------
// Slot g in [0,1024): LDS chunk g*16B (linear). Fragment semantics:
//   mblk=g>>7, s=(g>>6)&1, kq=(g>>4)&3, vv=g&15 -> v=mblk*16+vv, chunk j=(g>>4)&7
// Wave w computes rows [w*32, w*32+32) as 2 m-tiles.
// idxs table removed from LDS: 2-deep register pipeline (idx for k+1 loaded at k-1).
__global__ __launch_bounds__(256) void k_conv27m(const short* __restrict__ Ah_g,
                                                 const short* __restrict__ Al_g,
                                                 const int* __restrict__ nbr,
                                                 const short* __restrict__ Wh,
                                                 const short* __restrict__ Wl,
                                                 float* __restrict__ out,
                                                 float* __restrict__ stats, int Vout) {
  __shared__ alignas(16) short As_h[1024 * 8];  // 16 KB
  __shared__ alignas(16) short As_l[1024 * 8];  // 16 KB
  __shared__ float ss[128];
  const int tid = threadIdx.x;
  const int vb = blockIdx.x * 128;
  if (tid < 128) ss[tid] = 0.f;
  const int lane = tid & 63;
  const int w = tid >> 6;
  // staging slot geometry for this thread
  int sv[4], sj[4];
  bool svok[4];
#pragma unroll
  for (int it = 0; it < 4; ++it) {
    int g = it * 256 + tid;
    sv[it] = ((g >> 7) << 4) | (g & 15);
    sj[it] = (g >> 4) & 7;
    svok[it] = (vb + sv[it]) < Vout;
  }
  f32x4 acc[2][4];
#pragma unroll
  for (int m = 0; m < 2; ++m)
#pragma unroll
    for (int n = 0; n < 4; ++n)
#pragma unroll
      for (int r = 0; r < 4; ++r) acc[m][n][r] = 0.f;

  uint4 rg[8];
  int idxc[4], idxn[4];
  // prologue: idx(k=0), gather k=0, idx(k=1), write k=0
#pragma unroll
  for (int it = 0; it < 4; ++it)
    idxc[it] = svok[it] ? nbr[(size_t)(vb + sv[it]) * 27 + 0] : -1;
#pragma unroll
  for (int it = 0; it < 8; ++it) {
    int idx = idxc[it & 3];
    const short* src = (it < 4) ? Ah_g : Al_g;
    rg[it] = (idx >= 0) ? *(const uint4*)&src[(size_t)idx * 64 + sj[it & 3] * 8]
                        : make_uint4(0u, 0u, 0u, 0u);
  }
#pragma unroll
  for (int it = 0; it < 4; ++it)
    idxc[it] = svok[it] ? nbr[(size_t)(vb + sv[it]) * 27 + 1] : -1;
#pragma unroll
  for (int it = 0; it < 8; ++it) {
    int g = (it & 3) * 256 + tid;
    short* dst = (it < 4) ? As_h : As_l;
    *(uint4*)&dst[g * 8] = rg[it];
  }
  __syncthreads();

  for (int k = 0; k < 27; ++k) {
    if (k + 1 < 27) {
      // gather for k+1 (idx already in regs); issue before MFMA cluster
#pragma unroll
      for (int it = 0; it < 8; ++it) {
        int idx = idxc[it & 3];
        const short* src = (it < 4) ? Ah_g : Al_g;
        rg[it] = (idx >= 0) ? *(const uint4*)&src[(size_t)idx * 64 + sj[it & 3] * 8]
                            : make_uint4(0u, 0u, 0u, 0u);
      }
      if (k + 2 < 27) {
#pragma unroll
        for (int it = 0; it < 4; ++it)
          idxn[it] = svok[it] ? nbr[(size_t)(vb + sv[it]) * 27 + (k + 2)] : -1;
      }
    }
#pragma unroll
    for (int s = 0; s < 2; ++s) {
      short8 ah0 = *(const short8*)&As_h[((w * 4 + s) * 64 + lane) * 8];
      short8 al0 = *(const short8*)&As_l[((w * 4 + s) * 64 + lane) * 8];
      short8 ah1 = *(const short8*)&As_h[((w * 4 + 2 + s) * 64 + lane) * 8];
      short8 al1 = *(const short8*)&As_l[((w * 4 + 2 + s) * 64 + lane) * 8];
      const short* bph = Wh + ((size_t)(k * 2 + s) * 4) * 512;
      const short* bpl = Wl + ((size_t)(k * 2 + s) * 4) * 512;
#pragma unroll
      for (int n = 0; n < 4; ++n) {
        short8 bh = *(const short8*)&bph[n * 512 + lane * 8];
        short8 bl = *(const short8*)&bpl[n * 512 + lane * 8];
        acc[0][n] = __builtin_amdgcn_mfma_f32_16x16x32_bf16(ah0, bh, acc[0][n], 0, 0, 0);
        acc[0][n] = __builtin_amdgcn_mfma_f32_16x16x32_bf16(al0, bh, acc[0][n], 0, 0, 0);
        acc[0][n] = __builtin_amdgcn_mfma_f32_16x16x32_bf16(ah0, bl, acc[0][n], 0, 0, 0);
        acc[1][n] = __builtin_amdgcn_mfma_f32_16x16x32_bf16(ah1, bh, acc[1][n], 0, 0, 0);
        acc[1][n] = __builtin_amdgcn_mfma_f32_16x16x32_bf16(al1, bh, acc[1][n], 0, 0, 0);
        acc[1][n] = __builtin_amdgcn_mfma_f32_16x16x32_bf16(ah1, bl, acc[1][n], 0, 0, 0);
      }
    }
    __syncthreads();  // all waves done reading LDS for k
    if (k + 1 < 27) {
#pragma unroll
      for (int it = 0; it < 8; ++it) {
        int g = (it & 3) * 256 + tid;
        short* dst = (it < 4) ? As_h : As_l;
        *(uint4*)&dst[g * 8] = rg[it];
      }
      __syncthreads();  // k+1 staged
#pragma unroll
      for (int it = 0; it < 4; ++it) idxc[it] = idxn[it];
    }
  }

  const int col = lane & 15, rq = lane >> 4;
#pragma unroll
  for (int m = 0; m < 2; ++m) {
#pragma unroll
    for (int n = 0; n < 4; ++n) {
      int c = n * 16 + col;
      float s1 = 0.f, s2 = 0.f;
#pragma unroll
      for (int r = 0; r < 4; ++r) {
        int v = vb + w * 32 + m * 16 + rq * 4 + r;
        if (v < Vout) {
          float x = acc[m][n][r];
          out[(size_t)v * 64 + c] = x;
          s1 += x;
          s2 += x * x;
        }
      }
      atomicAdd(&ss[c], s1);
      atomicAdd(&ss[64 + c], s2);
    }
  }
  __syncthreads();
  if (tid < 128) atomicAdd(&stats[tid], ss[tid]);
}

// ---------------- vf3 = relu(bn2(h2)) + vf2 ----------------
__global__ void k_vf3(const float* __restrict__ h2, const float* __restrict__ vf2,
                      const float* __restrict__ sb2, float* __restrict__ vf3, int total) {
  int i = blockIdx.x * 256 + threadIdx.x;
  if (i >= total) return;
  int c = i & 63;
  vf3[i] = fmaxf(sb2[c] * h2[i] + sb2[64 + c], 0.f) + vf2[i];
}

// ---------------- pmm: raw = pfeat@Wpt + bpt -> pf2, + BN stats ----------------
__global__ __launch_bounds__(256) void k_pmm(const float* __restrict__ pfeat,
                                             const float* __restrict__ Wpt,
                                             const float* __restrict__ bpt,
                                             float* __restrict__ outbuf,
                                             float* __restrict__ stats, int N) {
  __shared__ float fs[64][128];
  __shared__ float Ws[64 * 64];
  __shared__ float ss[128];
  const int tid = threadIdx.x;
  const int pb = blockIdx.x * 128;
  for (int i = tid; i < 64 * 64; i += 256) Ws[i] = Wpt[i];
  if (tid < 128) ss[tid] = 0.f;
  const int srow = tid & 127, sci = (tid >> 7) * 32;
  int p = pb + srow;
  if (p < N) {
#pragma unroll
    for (int j = 0; j < 32; j += 4) {
      float4 t = *(const float4*)&pfeat[(size_t)p * 64 + sci + j];
      fs[sci + j + 0][srow] = t.x;
      fs[sci + j + 1][srow] = t.y;
      fs[sci + j + 2][srow] = t.z;
      fs[sci + j + 3][srow] = t.w;
    }
  } else {
#pragma unroll
    for (int j = 0; j < 32; ++j) fs[sci + j][srow] = 0.f;
  }
  __syncthreads();
  const int vq = tid & 15, cq = tid >> 4;
  const int p0 = vq * 8, c0 = cq * 4;
  float acc[8][4];
#pragma unroll
  for (int r = 0; r < 8; ++r)
#pragma unroll
    for (int q = 0; q < 4; ++q) acc[r][q] = 0.f;
#pragma unroll 8
  for (int ci = 0; ci < 64; ++ci) {
    float4 w4 = *(const float4*)&Ws[ci * 64 + c0];
    float4 fa = *(const float4*)&fs[ci][p0];
    float4 fb = *(const float4*)&fs[ci][p0 + 4];
    float fv[8] = {fa.x, fa.y, fa.z, fa.w, fb.x, fb.y, fb.z, fb.w};
    float wv[4] = {w4.x, w4.y, w4.z, w4.w};
#pragma unroll
    for (int r = 0; r < 8; ++r)
#pragma unroll
      for (int q = 0; q < 4; ++q) acc[r][q] += fv[r] * wv[q];
  }
  float bb[4] = {bpt[c0], bpt[c0 + 1], bpt[c0 + 2], bpt[c0 + 3]};
  float s1[4] = {0, 0, 0, 0}, s2[4] = {0, 0, 0, 0};
#pragma unroll
  for (int r = 0; r < 8; ++r) {
    int pp = pb + p0 + r;
    if (pp < N) {
      float4 o;
      o.x = acc[r][0] + bb[0];
      o.y = acc[r][1] + bb[1];
      o.z = acc[r][2] + bb[2];
      o.w = acc[r][3] + bb[3];
      *(float4*)&outbuf[(size_t)pp * 64 + c0] = o;
      s1[0] += o.x; s2[0] += o.x * o.x;
      s1[1] += o.y; s2[1] += o.y * o.y;
      s1[2] += o.z; s2[2] += o.z * o.z;
      s1[3] += o.w; s2[3] += o.w * o.w;
    }
  }
#pragma unroll
  for (int q = 0; q < 4; ++q) {
    atomicAdd(&ss[c0 + q], s1[q]);
    atomicAdd(&ss[64 + c0 + q], s2[q]);
  }
  __syncthreads();
  if (tid < 128) atomicAdd(&stats[tid], ss[tid]);
}

// ---------------- tri2 fused with final seg_mean ----------------
__global__ __launch_bounds__(256) void k_tri2v(const float* __restrict__ vf3,
                                               const float* __restrict__ sb3,
                                               const int* __restrict__ tidx,
                                               const float* __restrict__ twt,
                                               const int* __restrict__ starts,
                                               const float* __restrict__ cnt,
                                               const int* __restrict__ plist,
                                               float* __restrict__ pf2,
                                               float* __restrict__ vf4, int V) {
  int t = threadIdx.x;
  int v = blockIdx.x * 4 + (t >> 6);
  int c = t & 63;
  if (v >= V) return;
  int s0 = starts[v];
  int n = (int)cnt[v];
  if (n < 1) return;
  int p0 = plist[s0];
  float S[8];
#pragma unroll
  for (int j = 0; j < 8; ++j) {
    int idx = tidx[(size_t)p0 * 8 + j];
    S[j] = (idx >= 0) ? vf3[(size_t)idx * 64 + c] : 0.f;
  }
  float s3 = sb3[c], b3 = sb3[64 + c];
  float acc_v = 0.f;
  for (int i = 0; i < n; ++i) {
    int p = plist[s0 + i];
    float4 w0 = *(const float4*)&twt[(size_t)p * 8];
    float4 w1 = *(const float4*)&twt[(size_t)p * 8 + 4];
    float raw = pf2[(size_t)p * 64 + c];
    float val = fmaxf(s3 * raw + b3, 0.f) +
                w0.x * S[0] + w0.y * S[1] + w0.z * S[2] + w0.w * S[3] +
                w1.x * S[4] + w1.y * S[5] + w1.z * S[6] + w1.w * S[7];
    pf2[(size_t)p * 64 + c] = val;
    acc_v += val;
  }
  vf4[(size_t)v * 64 + c] = acc_v / (float)n;
}

extern "C" void kernel_launch(void* const* d_in, const int* in_sizes, int n_in,
                              void* d_out, int out_size, void* d_ws, size_t ws_size,
                              hipStream_t stream) {
  const float* pf = (const float*)d_in[0];
  const float* Wc = (const float*)d_in[1];
  const float* g1 = (const float*)d_in[2];
  const float* b1 = (const float*)d_in[3];
  const float* Wr1 = (const float*)d_in[4];
  const float* gr1 = (const float*)d_in[5];
  const float* br1 = (const float*)d_in[6];
  const float* Wr2 = (const float*)d_in[7];
  const float* gr2 = (const float*)d_in[8];
  const float* br2 = (const float*)d_in[9];
  const float* Wpt = (const float*)d_in[10];
  const float* bpt = (const float*)d_in[11];
  const float* gp = (const float*)d_in[12];
  const float* bp = (const float*)d_in[13];
  const float* twt = (const float*)d_in[14];
  const float* cnt_in = (const float*)d_in[15];
  const float* cnt_out = (const float*)d_in[16];
  const int* p2v_in = (const int*)d_in[17];
  const int* conv_map = (const int*)d_in[18];
  const int* nbr27 = (const int*)d_in[19];
  const int* tri_idx = (const int*)d_in[20];
  const int* p2v_out = (const int*)d_in[21];

  const int N = in_sizes[0] / 32;
  const int Vin = in_sizes[15];
  const int Vout = in_sizes[16];

  float* ws = (float*)d_ws;
  size_t o = 0;
  auto alloc = [&](size_t nf) {
    float* pbase = ws + o;
    o += (nf + 63) & ~(size_t)63;
    return pbase;
  };
  size_t vf0_sz = (size_t)Vin * 32;
  size_t vf3_sz = (size_t)Vout * 64;
  float* vf0 = alloc(vf0_sz > vf3_sz ? vf0_sz : vf3_sz);  // vf3 aliases vf0
  float* c1 = alloc((size_t)Vout * 64);                   // h2 aliases c1
  float* pfeat = alloc((size_t)N * 64);                   // bf16 split arrays alias after pmm
  float* vf2 = alloc((size_t)Vout * 64);
  float* h1 = alloc((size_t)Vout * 64);
  float* stats = alloc(512);
  float* sb = alloc(512);
  int* partial = (int*)alloc(1024);
  int* starts = (int*)alloc(Vout);
  int* cursor = (int*)alloc(Vout);
  int* plist = (int*)alloc(N);
  const int WFRAG = 27 * 2 * 4 * 64 * 8;  // shorts
  short* Wh1 = (short*)alloc(WFRAG / 2);
  short* Wl1 = (short*)alloc(WFRAG / 2);
  short* Wh2 = (short*)alloc(WFRAG / 2);
  short* Wl2 = (short*)alloc(WFRAG / 2);
  float* vf3 = vf0;
  float* h2 = c1;
  short* vf2h = (short*)pfeat;
  short* vf2l = vf2h + (size_t)Vout * 64;
  short* h1rh = vf2l + (size_t)Vout * 64;
  short* h1rl = h1rh + (size_t)Vout * 64;

  float* vf4 = (float*)d_out;
  float* pf2 = vf4 + (size_t)Vout * 64;

  const int nb = CDIV(Vout, 1024);

  hipMemsetAsync(vf0, 0, (size_t)Vin * 32 * sizeof(float), stream);
  hipMemsetAsync(stats, 0, 512 * sizeof(float), stream);

  k_scatter_in<<<CDIV(N * 32, 256), 256, 0, stream>>>(pf, p2v_in, vf0, N * 32);
  k_div_in<<<CDIV(Vin * 32, 256), 256, 0, stream>>>(vf0, cnt_in, Vin * 32);
  k_conv1<<<CDIV(Vout, 128), 256, 0, stream>>>(vf0, conv_map, Wc, c1, stats, Vout);
  k_bnfin<<<1, 64, 0, stream>>>(stats, g1, b1, sb, Vout);

  // counting sort voxel->points
  k_scan_part<<<nb, 1024, 0, stream>>>(cnt_out, partial, Vout);
  k_scan_top<<<1, 1024, 0, stream>>>(partial, nb);
  k_scan_write<<<nb, 1024, 0, stream>>>(cnt_out, partial, starts, cursor, Vout);
  k_bucket<<<CDIV(N, 256), 256, 0, stream>>>(p2v_out, cursor, plist, N);

  // weight prep for both convs
  k_wprep<<<CDIV(27 * 2 * 4 * 64, 256), 256, 0, stream>>>(Wr1, Wh1, Wl1, 27);
  k_wprep<<<CDIV(27 * 2 * 4 * 64, 256), 256, 0, stream>>>(Wr2, Wh2, Wl2, 27);

  // fused tri1 + seg_mean -> pfeat, vf2
  k_tri1v<<<CDIV(Vout, 4), 256, 0, stream>>>(c1, sb, tri_idx, twt, starts, cnt_out,
                                             plist, pfeat, vf2, Vout);

  // pmm raw + stats (pfeat dead afterwards)
  k_pmm<<<CDIV(N, 128), 256, 0, stream>>>(pfeat, Wpt, bpt, pf2, stats + 384, N);
  k_bnfin<<<1, 64, 0, stream>>>(stats + 384, gp, bp, sb + 384, N);

  // conv block 1
  k_split<<<CDIV(Vout * 64, 256), 256, 0, stream>>>(vf2, nullptr, vf2h, vf2l, Vout * 64);
  k_conv27m<<<CDIV(Vout, 128), 256, 0, stream>>>(vf2h, vf2l, nbr27, Wh1, Wl1, h1,
                                                 stats + 128, Vout);
  k_bnfin<<<1, 64, 0, stream>>>(stats + 128, gr1, br1, sb + 128, Vout);

  // conv block 2
  k_split<<<CDIV(Vout * 64, 256), 256, 0, stream>>>(h1, sb + 128, h1rh, h1rl, Vout * 64);
  k_conv27m<<<CDIV(Vout, 128), 256, 0, stream>>>(h1rh, h1rl, nbr27, Wh2, Wl2, h2,
                                                 stats + 256, Vout);
  k_bnfin<<<1, 64, 0, stream>>>(stats + 256, gr2, br2, sb + 256, Vout);

  k_vf3<<<CDIV(Vout * 64, 256), 256, 0, stream>>>(h2, vf2, sb + 256, vf3, Vout * 64);

  // fused tri2 + final seg_mean -> pf2, vf4
  k_tri2v<<<CDIV(Vout, 4), 256, 0, stream>>>(vf3, sb + 384, tri_idx, twt, starts,
                                             cnt_out, plist, pf2, vf4, Vout);
}

// Round 7
// 1235.616 us; speedup vs baseline: 1.1336x; 1.1336x over previous
//
#include <hip/hip_runtime.h>

#define EPSV 1e-5f
#define CDIV(a, b) (((a) + (b) - 1) / (b))

using short8 = __attribute__((ext_vector_type(8))) short;
using f32x4 = __attribute__((ext_vector_type(4))) float;

__device__ __forceinline__ unsigned short bf16rne(float x) {
  unsigned u = __float_as_uint(x);
  unsigned r = (u + 0x7fffu + ((u >> 16) & 1u)) >> 16;
  return (unsigned short)r;
}

// ---------------- stage 0: seg_mean(pf, p2v_in) ----------------
__global__ void k_scatter_in(const float* __restrict__ pf, const int* __restrict__ p2v,
                             float* __restrict__ vf0, int total) {
  int i = blockIdx.x * 256 + threadIdx.x;
  if (i >= total) return;
  atomicAdd(&vf0[(size_t)p2v[i >> 5] * 32 + (i & 31)], pf[i]);
}

__global__ void k_div_in(float* __restrict__ vf0, const float* __restrict__ cnt, int total) {
  int i = blockIdx.x * 256 + threadIdx.x;
  if (i >= total) return;
  vf0[i] /= cnt[i >> 5];
}

// ---------------- conv1: 8-tap, 32->64, fp32 VALU, + BN stats ----------------
__global__ __launch_bounds__(256) void k_conv1(const float* __restrict__ vin,
                                               const int* __restrict__ cmap,
                                               const float* __restrict__ W,  // [8][32][64]
                                               float* __restrict__ out,
                                               float* __restrict__ stats, int Vout) {
  __shared__ float fs[32][128];
  __shared__ float Ws[32 * 64];
  __shared__ int idxs[128 * 8];
  __shared__ float ss[128];
  const int tid = threadIdx.x;
  const int vb = blockIdx.x * 128;
  for (int i = tid; i < 128 * 8; i += 256) {
    int g = vb * 8 + i;
    idxs[i] = (g < Vout * 8) ? cmap[g] : -1;
  }
  if (tid < 128) ss[tid] = 0.f;
  const int vq = tid & 15, cq = tid >> 4;
  const int v0 = vq * 8, c0 = cq * 4;
  const int srow = tid & 127, sci = (tid >> 7) * 16;
  float acc[8][4];
#pragma unroll
  for (int r = 0; r < 8; ++r)
#pragma unroll
    for (int q = 0; q < 4; ++q) acc[r][q] = 0.f;

  for (int k = 0; k < 8; ++k) {
    __syncthreads();
    for (int i = tid; i < 32 * 64; i += 256) Ws[i] = W[k * 2048 + i];
    int idx = idxs[srow * 8 + k];
    if (idx >= 0) {
#pragma unroll
      for (int j = 0; j < 16; j += 4) {
        float4 t = *(const float4*)&vin[(size_t)idx * 32 + sci + j];
        fs[sci + j + 0][srow] = t.x;
        fs[sci + j + 1][srow] = t.y;
        fs[sci + j + 2][srow] = t.z;
        fs[sci + j + 3][srow] = t.w;
      }
    } else {
#pragma unroll
      for (int j = 0; j < 16; ++j) fs[sci + j][srow] = 0.f;
    }
    __syncthreads();
#pragma unroll 8
    for (int ci = 0; ci < 32; ++ci) {
      float4 w4 = *(const float4*)&Ws[ci * 64 + c0];
      float4 fa = *(const float4*)&fs[ci][v0];
      float4 fb = *(const float4*)&fs[ci][v0 + 4];
      float fv[8] = {fa.x, fa.y, fa.z, fa.w, fb.x, fb.y, fb.z, fb.w};
      float wv[4] = {w4.x, w4.y, w4.z, w4.w};
#pragma unroll
      for (int r = 0; r < 8; ++r)
#pragma unroll
        for (int q = 0; q < 4; ++q) acc[r][q] += fv[r] * wv[q];
    }
  }
  float s1[4] = {0, 0, 0, 0}, s2[4] = {0, 0, 0, 0};
#pragma unroll
  for (int r = 0; r < 8; ++r) {
    int v = vb + v0 + r;
    if (v < Vout) {
      *(float4*)&out[(size_t)v * 64 + c0] =
          make_float4(acc[r][0], acc[r][1], acc[r][2], acc[r][3]);
#pragma unroll
      for (int q = 0; q < 4; ++q) {
        float x = acc[r][q];
        s1[q] += x;
        s2[q] += x * x;
      }
    }
  }
#pragma unroll
  for (int q = 0; q < 4; ++q) {
    atomicAdd(&ss[c0 + q], s1[q]);
    atomicAdd(&ss[64 + c0 + q], s2[q]);
  }
  __syncthreads();
  if (tid < 128) atomicAdd(&stats[tid], ss[tid]);
}

// ---------------- BN finalize ----------------
__global__ void k_bnfin(const float* __restrict__ stats, const float* __restrict__ g,
                        const float* __restrict__ b, float* __restrict__ sb, int rows) {
  int c = threadIdx.x;
  float inv = 1.f / (float)rows;
  float m = stats[c] * inv;
  float v = stats[64 + c] * inv - m * m;
  float sc = g[c] * rsqrtf(v + EPSV);
  sb[c] = sc;
  sb[64 + c] = b[c] - m * sc;
}

// ---------------- counting sort: voxel -> point list ----------------
__global__ __launch_bounds__(1024) void k_scan_part(const float* __restrict__ cnt,
                                                    int* __restrict__ partial, int V) {
  __shared__ int s[1024];
  int i = blockIdx.x * 1024 + threadIdx.x;
  s[threadIdx.x] = (i < V) ? (int)cnt[i] : 0;
  __syncthreads();
  for (int st = 512; st > 0; st >>= 1) {
    if (threadIdx.x < st) s[threadIdx.x] += s[threadIdx.x + st];
    __syncthreads();
  }
  if (threadIdx.x == 0) partial[blockIdx.x] = s[0];
}

__global__ __launch_bounds__(1024) void k_scan_top(int* __restrict__ partial, int nb) {
  __shared__ int s[1024];
  int t = threadIdx.x;
  int orig = (t < nb) ? partial[t] : 0;
  s[t] = orig;
  __syncthreads();
  for (int st = 1; st < 1024; st <<= 1) {
    int v = (t >= st) ? s[t - st] : 0;
    __syncthreads();
    s[t] += v;
    __syncthreads();
  }
  if (t < nb) partial[t] = s[t] - orig;  // exclusive
}

__global__ __launch_bounds__(1024) void k_scan_write(const float* __restrict__ cnt,
                                                     const int* __restrict__ partial,
                                                     int* __restrict__ starts,
                                                     int* __restrict__ cursor, int V) {
  __shared__ int s[1024];
  int t = threadIdx.x;
  int i = blockIdx.x * 1024 + t;
  int orig = (i < V) ? (int)cnt[i] : 0;
  s[t] = orig;
  __syncthreads();
  for (int st = 1; st < 1024; st <<= 1) {
    int v = (t >= st) ? s[t - st] : 0;
    __syncthreads();
    s[t] += v;
    __syncthreads();
  }
  if (i < V) {
    int excl = s[t] - orig + partial[blockIdx.x];
    starts[i] = excl;
    cursor[i] = excl;
  }
}

__global__ void k_bucket(const int* __restrict__ p2v, int* __restrict__ cursor,
                         int* __restrict__ plist, int N) {
  int p = blockIdx.x * 256 + threadIdx.x;
  if (p >= N) return;
  int pos = atomicAdd(&cursor[p2v[p]], 1);
  plist[pos] = p;
}

// ---------------- tri1 fused with seg_mean: per-voxel corner gather ----------------
__global__ __launch_bounds__(256) void k_tri1v(const float* __restrict__ c1,
                                               const float* __restrict__ sb0,
                                               const int* __restrict__ tidx,
                                               const float* __restrict__ twt,
                                               const int* __restrict__ starts,
                                               const float* __restrict__ cnt,
                                               const int* __restrict__ plist,
                                               float* __restrict__ pfeat,
                                               float* __restrict__ vf2, int V) {
  int t = threadIdx.x;
  int v = blockIdx.x * 4 + (t >> 6);
  int c = t & 63;
  if (v >= V) return;
  int s0 = starts[v];
  int n = (int)cnt[v];
  if (n < 1) return;
  int p0 = plist[s0];
  float sc = sb0[c], bi = sb0[64 + c];
  float R[8];
#pragma unroll
  for (int j = 0; j < 8; ++j) {
    int idx = tidx[(size_t)p0 * 8 + j];
    R[j] = (idx >= 0) ? fmaxf(sc * c1[(size_t)idx * 64 + c] + bi, 0.f) : 0.f;
  }
  float acc_v = 0.f;
  for (int i = 0; i < n; ++i) {
    int p = plist[s0 + i];
    float4 w0 = *(const float4*)&twt[(size_t)p * 8];
    float4 w1 = *(const float4*)&twt[(size_t)p * 8 + 4];
    float acc = w0.x * R[0] + w0.y * R[1] + w0.z * R[2] + w0.w * R[3] +
                w1.x * R[4] + w1.y * R[5] + w1.z * R[6] + w1.w * R[7];
    pfeat[(size_t)p * 64 + c] = acc;
    acc_v += acc;
  }
  vf2[(size_t)v * 64 + c] = acc_v / (float)n;
}

// ---------------- weight prep: W[k][ci][co] f32 -> fragment-linear bf16 hi/lo ----------------
__global__ void k_wprep(const float* __restrict__ W, short* __restrict__ Wh,
                        short* __restrict__ Wl, int ntap) {
  int t = blockIdx.x * 256 + threadIdx.x;
  int total = ntap * 2 * 4 * 64;
  if (t >= total) return;
  int l = t & 63;
  int n = (t >> 6) & 3;
  int s = (t >> 8) & 1;
  int k = t >> 9;
  int co = n * 16 + (l & 15);
  int ci0 = s * 32 + (l >> 4) * 8;
#pragma unroll
  for (int j = 0; j < 8; ++j) {
    float x = W[((size_t)(k * 64 + ci0 + j)) * 64 + co];
    unsigned short hb = bf16rne(x);
    float hf = __uint_as_float((unsigned)hb << 16);
    Wh[(size_t)t * 8 + j] = (short)hb;
    Wl[(size_t)t * 8 + j] = (short)bf16rne(x - hf);
  }
}

// ---------------- split: fp32 -> packed bf16 hi/lo rows (256B/voxel), fused BN+ReLU ----------------
// packed[v*128 + c] = hi, packed[v*128 + 64 + c] = lo
__global__ void k_split(const float* __restrict__ in, const float* __restrict__ sb,
                        short* __restrict__ packed, int total) {
  int i = blockIdx.x * 256 + threadIdx.x;
  if (i >= total) return;
  int c = i & 63;
  float x = in[i];
  if (sb) x = fmaxf(sb[c] * x + sb[64 + c], 0.f);
  unsigned short hb = bf16rne(x);
  float hf = __uint_as_float((unsigned)hb << 16);
  size_t base = (size_t)(i >> 6) * 128 + c;
  packed[base] = (short)hb;
  packed[base + 64] = (short)bf16rne(x - hf);
}

// ---------------- conv27 register-direct MFMA: no LDS staging, no barriers ----------------
// Wave (64 lanes) owns 32 voxels (2 m-tiles of 16). lane l: vv=l&15, kq=l>>4.
// A-frag of mfma_f32_16x16x32_bf16: lane holds A[vv][kq*8+j], j=0..7 -> a single
// per-lane global_load_dwordx4 from packed[idx*128 + half*64 + s*32 + kq*8].
// Software pipeline: A(k+1) gather issued before MFMA(k); idx(k+2) prefetched.
__global__ __launch_bounds__(256) void k_conv27r(const short* __restrict__ A_g,
                                                 const int* __restrict__ nbr,
                                                 const short* __restrict__ Wh,
                                                 const short* __restrict__ Wl,
                                                 float* __restrict__ out,
                                                 float* __restrict__ stats, int Vout) {
  __shared__ float ss[128];
  const int tid = threadIdx.x;
  const int lane = tid & 63;
  const int w = tid >> 6;
  const int vb = blockIdx.x * 128 + w * 32;
  if (tid < 128) ss[tid] = 0.f;
  const int vv = lane & 15, kq = lane >> 4;
  const int v0 = vb + vv, v1 = vb + 16 + vv;
  const bool ok0 = v0 < Vout, ok1 = v1 < Vout;
  const int koff = kq * 8;

  f32x4 acc[2][4];
#pragma unroll
  for (int m = 0; m < 2; ++m)
#pragma unroll
    for (int n = 0; n < 4; ++n)
#pragma unroll
      for (int r = 0; r < 4; ++r) acc[m][n][r] = 0.f;

  auto ldA = [&](int idx, int off) -> short8 {
    if (idx < 0) {
      short8 z = 0;
      return z;
    }
    return *(const short8*)&A_g[(size_t)idx * 128 + off];
  };

  // cA/nA layout: [m*4 + s*2 + half]; off = half*64 + s*32 + koff
  short8 cA[8], nA[8];
  int idn0, idn1;

  // prologue: A(0), idx(1)
  {
    int i0 = ok0 ? nbr[(size_t)v0 * 27] : -1;
    int i1 = ok1 ? nbr[(size_t)v1 * 27] : -1;
#pragma unroll
    for (int s = 0; s < 2; ++s)
#pragma unroll
      for (int h = 0; h < 2; ++h) {
        cA[s * 2 + h] = ldA(i0, h * 64 + s * 32 + koff);
        cA[4 + s * 2 + h] = ldA(i1, h * 64 + s * 32 + koff);
      }
    idn0 = ok0 ? nbr[(size_t)v0 * 27 + 1] : -1;
    idn1 = ok1 ? nbr[(size_t)v1 * 27 + 1] : -1;
  }

  for (int k = 0; k < 27; ++k) {
    int idf0 = -1, idf1 = -1;
    if (k + 1 < 27) {
      // issue A(k+1) gathers (latency hidden under MFMA cluster below)
#pragma unroll
      for (int s = 0; s < 2; ++s)
#pragma unroll
        for (int h = 0; h < 2; ++h) {
          nA[s * 2 + h] = ldA(idn0, h * 64 + s * 32 + koff);
          nA[4 + s * 2 + h] = ldA(idn1, h * 64 + s * 32 + koff);
        }
      if (k + 2 < 27) {
        idf0 = ok0 ? nbr[(size_t)v0 * 27 + (k + 2)] : -1;
        idf1 = ok1 ? nbr[(size_t)v1 * 27 + (k + 2)] : -1;
      }
    }
    const short* bkh = Wh + (size_t)k * 4096 + lane * 8;
    const short* bkl = Wl + (size_t)k * 4096 + lane * 8;
#pragma unroll
    for (int s = 0; s < 2; ++s) {
      short8 ah0 = cA[s * 2], al0 = cA[s * 2 + 1];
      short8 ah1 = cA[4 + s * 2], al1 = cA[4 + s * 2 + 1];
#pragma unroll
      for (int n = 0; n < 4; ++n) {
        short8 bh = *(const short8*)&bkh[(s * 4 + n) * 512];
        short8 bl = *(const short8*)&bkl[(s * 4 + n) * 512];
        acc[0][n] = __builtin_amdgcn_mfma_f32_16x16x32_bf16(ah0, bh, acc[0][n], 0, 0, 0);
        acc[0][n] = __builtin_amdgcn_mfma_f32_16x16x32_bf16(al0, bh, acc[0][n], 0, 0, 0);
        acc[0][n] = __builtin_amdgcn_mfma_f32_16x16x32_bf16(ah0, bl, acc[0][n], 0, 0, 0);
        acc[1][n] = __builtin_amdgcn_mfma_f32_16x16x32_bf16(ah1, bh, acc[1][n], 0, 0, 0);
        acc[1][n] = __builtin_amdgcn_mfma_f32_16x16x32_bf16(al1, bh, acc[1][n], 0, 0, 0);
        acc[1][n] = __builtin_amdgcn_mfma_f32_16x16x32_bf16(ah1, bl, acc[1][n], 0, 0, 0);
      }
    }
    if (k + 1 < 27) {
#pragma unroll
      for (int q = 0; q < 8; ++q) cA[q] = nA[q];
      idn0 = idf0;
      idn1 = idf1;
    }
  }

  const int col = lane & 15, rq = lane >> 4;
  __syncthreads();  // ss init visible
#pragma unroll
  for (int m = 0; m < 2; ++m) {
#pragma unroll
    for (int n = 0; n < 4; ++n) {
      int c = n * 16 + col;
      float s1 = 0.f, s2 = 0.f;
#pragma unroll
      for (int r = 0; r < 4; ++r) {
        int v = vb + m * 16 + rq * 4 + r;
        if (v < Vout) {
          float x = acc[m][n][r];
          out[(size_t)v * 64 + c] = x;
          s1 += x;
          s2 += x * x;
        }
      }
      atomicAdd(&ss[c], s1);
      atomicAdd(&ss[64 + c], s2);
    }
  }
  __syncthreads();
  if (tid < 128) atomicAdd(&stats[tid], ss[tid]);
}

// ---------------- vf3 = relu(bn2(h2)) + vf2 ----------------
__global__ void k_vf3(const float* __restrict__ h2, const float* __restrict__ vf2,
                      const float* __restrict__ sb2, float* __restrict__ vf3, int total) {
  int i = blockIdx.x * 256 + threadIdx.x;
  if (i >= total) return;
  int c = i & 63;
  vf3[i] = fmaxf(sb2[c] * h2[i] + sb2[64 + c], 0.f) + vf2[i];
}

// ---------------- pmm: raw = pfeat@Wpt + bpt -> pf2, + BN stats ----------------
__global__ __launch_bounds__(256) void k_pmm(const float* __restrict__ pfeat,
                                             const float* __restrict__ Wpt,
                                             const float* __restrict__ bpt,
                                             float* __restrict__ outbuf,
                                             float* __restrict__ stats, int N) {
  __shared__ float fs[64][128];
  __shared__ float Ws[64 * 64];
  __shared__ float ss[128];
  const int tid = threadIdx.x;
  const int pb = blockIdx.x * 128;
  for (int i = tid; i < 64 * 64; i += 256) Ws[i] = Wpt[i];
  if (tid < 128) ss[tid] = 0.f;
  const int srow = tid & 127, sci = (tid >> 7) * 32;
  int p = pb + srow;
  if (p < N) {
#pragma unroll
    for (int j = 0; j < 32; j += 4) {
      float4 t = *(const float4*)&pfeat[(size_t)p * 64 + sci + j];
      fs[sci + j + 0][srow] = t.x;
      fs[sci + j + 1][srow] = t.y;
      fs[sci + j + 2][srow] = t.z;
      fs[sci + j + 3][srow] = t.w;
    }
  } else {
#pragma unroll
    for (int j = 0; j < 32; ++j) fs[sci + j][srow] = 0.f;
  }
  __syncthreads();
  const int vq = tid & 15, cq = tid >> 4;
  const int p0 = vq * 8, c0 = cq * 4;
  float acc[8][4];
#pragma unroll
  for (int r = 0; r < 8; ++r)
#pragma unroll
    for (int q = 0; q < 4; ++q) acc[r][q] = 0.f;
#pragma unroll 8
  for (int ci = 0; ci < 64; ++ci) {
    float4 w4 = *(const float4*)&Ws[ci * 64 + c0];
    float4 fa = *(const float4*)&fs[ci][p0];
    float4 fb = *(const float4*)&fs[ci][p0 + 4];
    float fv[8] = {fa.x, fa.y, fa.z, fa.w, fb.x, fb.y, fb.z, fb.w};
    float wv[4] = {w4.x, w4.y, w4.z, w4.w};
#pragma unroll
    for (int r = 0; r < 8; ++r)
#pragma unroll
      for (int q = 0; q < 4; ++q) acc[r][q] += fv[r] * wv[q];
  }
  float bb[4] = {bpt[c0], bpt[c0 + 1], bpt[c0 + 2], bpt[c0 + 3]};
  float s1[4] = {0, 0, 0, 0}, s2[4] = {0, 0, 0, 0};
#pragma unroll
  for (int r = 0; r < 8; ++r) {
    int pp = pb + p0 + r;
    if (pp < N) {
      float4 o;
      o.x = acc[r][0] + bb[0];
      o.y = acc[r][1] + bb[1];
      o.z = acc[r][2] + bb[2];
      o.w = acc[r][3] + bb[3];
      *(float4*)&outbuf[(size_t)pp * 64 + c0] = o;
      s1[0] += o.x; s2[0] += o.x * o.x;
      s1[1] += o.y; s2[1] += o.y * o.y;
      s1[2] += o.z; s2[2] += o.z * o.z;
      s1[3] += o.w; s2[3] += o.w * o.w;
    }
  }
#pragma unroll
  for (int q = 0; q < 4; ++q) {
    atomicAdd(&ss[c0 + q], s1[q]);
    atomicAdd(&ss[64 + c0 + q], s2[q]);
  }
  __syncthreads();
  if (tid < 128) atomicAdd(&stats[tid], ss[tid]);
}

// ---------------- tri2 fused with final seg_mean ----------------
__global__ __launch_bounds__(256) void k_tri2v(const float* __restrict__ vf3,
                                               const float* __restrict__ sb3,
                                               const int* __restrict__ tidx,
                                               const float* __restrict__ twt,
                                               const int* __restrict__ starts,
                                               const float* __restrict__ cnt,
                                               const int* __restrict__ plist,
                                               float* __restrict__ pf2,
                                               float* __restrict__ vf4, int V) {
  int t = threadIdx.x;
  int v = blockIdx.x * 4 + (t >> 6);
  int c = t & 63;
  if (v >= V) return;
  int s0 = starts[v];
  int n = (int)cnt[v];
  if (n < 1) return;
  int p0 = plist[s0];
  float S[8];
#pragma unroll
  for (int j = 0; j < 8; ++j) {
    int idx = tidx[(size_t)p0 * 8 + j];
    S[j] = (idx >= 0) ? vf3[(size_t)idx * 64 + c] : 0.f;
  }
  float s3 = sb3[c], b3 = sb3[64 + c];
  float acc_v = 0.f;
  for (int i = 0; i < n; ++i) {
    int p = plist[s0 + i];
    float4 w0 = *(const float4*)&twt[(size_t)p * 8];
    float4 w1 = *(const float4*)&twt[(size_t)p * 8 + 4];
    float raw = pf2[(size_t)p * 64 + c];
    float val = fmaxf(s3 * raw + b3, 0.f) +
                w0.x * S[0] + w0.y * S[1] + w0.z * S[2] + w0.w * S[3] +
                w1.x * S[4] + w1.y * S[5] + w1.z * S[6] + w1.w * S[7];
    pf2[(size_t)p * 64 + c] = val;
    acc_v += val;
  }
  vf4[(size_t)v * 64 + c] = acc_v / (float)n;
}

extern "C" void kernel_launch(void* const* d_in, const int* in_sizes, int n_in,
                              void* d_out, int out_size, void* d_ws, size_t ws_size,
                              hipStream_t stream) {
  const float* pf = (const float*)d_in[0];
  const float* Wc = (const float*)d_in[1];
  const float* g1 = (const float*)d_in[2];
  const float* b1 = (const float*)d_in[3];
  const float* Wr1 = (const float*)d_in[4];
  const float* gr1 = (const float*)d_in[5];
  const float* br1 = (const float*)d_in[6];
  const float* Wr2 = (const float*)d_in[7];
  const float* gr2 = (const float*)d_in[8];
  const float* br2 = (const float*)d_in[9];
  const float* Wpt = (const float*)d_in[10];
  const float* bpt = (const float*)d_in[11];
  const float* gp = (const float*)d_in[12];
  const float* bp = (const float*)d_in[13];
  const float* twt = (const float*)d_in[14];
  const float* cnt_in = (const float*)d_in[15];
  const float* cnt_out = (const float*)d_in[16];
  const int* p2v_in = (const int*)d_in[17];
  const int* conv_map = (const int*)d_in[18];
  const int* nbr27 = (const int*)d_in[19];
  const int* tri_idx = (const int*)d_in[20];
  const int* p2v_out = (const int*)d_in[21];

  const int N = in_sizes[0] / 32;
  const int Vin = in_sizes[15];
  const int Vout = in_sizes[16];

  float* ws = (float*)d_ws;
  size_t o = 0;
  auto alloc = [&](size_t nf) {
    float* pbase = ws + o;
    o += (nf + 63) & ~(size_t)63;
    return pbase;
  };
  size_t vf0_sz = (size_t)Vin * 32;
  size_t vf3_sz = (size_t)Vout * 64;
  float* vf0 = alloc(vf0_sz > vf3_sz ? vf0_sz : vf3_sz);  // vf3 aliases vf0
  float* c1 = alloc((size_t)Vout * 64);                   // h2 aliases c1
  float* pfeat = alloc((size_t)N * 64);                   // packed bf16 arrays alias after pmm
  float* vf2 = alloc((size_t)Vout * 64);
  float* h1 = alloc((size_t)Vout * 64);
  float* stats = alloc(512);
  float* sb = alloc(512);
  int* partial = (int*)alloc(1024);
  int* starts = (int*)alloc(Vout);
  int* cursor = (int*)alloc(Vout);
  int* plist = (int*)alloc(N);
  const int WFRAG = 27 * 2 * 4 * 64 * 8;  // shorts
  short* Wh1 = (short*)alloc(WFRAG / 2);
  short* Wl1 = (short*)alloc(WFRAG / 2);
  short* Wh2 = (short*)alloc(WFRAG / 2);
  short* Wl2 = (short*)alloc(WFRAG / 2);
  float* vf3 = vf0;
  float* h2 = c1;
  // packed bf16 hi/lo rows (256B/voxel), aliasing pfeat (dead after k_pmm):
  // 2 arrays x Vout*128 shorts = Vout*128 floats <= N*64 floats
  short* vf2p = (short*)pfeat;
  short* h1p = vf2p + (size_t)Vout * 128;

  float* vf4 = (float*)d_out;
  float* pf2 = vf4 + (size_t)Vout * 64;

  const int nb = CDIV(Vout, 1024);

  hipMemsetAsync(vf0, 0, (size_t)Vin * 32 * sizeof(float), stream);
  hipMemsetAsync(stats, 0, 512 * sizeof(float), stream);

  k_scatter_in<<<CDIV(N * 32, 256), 256, 0, stream>>>(pf, p2v_in, vf0, N * 32);
  k_div_in<<<CDIV(Vin * 32, 256), 256, 0, stream>>>(vf0, cnt_in, Vin * 32);
  k_conv1<<<CDIV(Vout, 128), 256, 0, stream>>>(vf0, conv_map, Wc, c1, stats, Vout);
  k_bnfin<<<1, 64, 0, stream>>>(stats, g1, b1, sb, Vout);

  // counting sort voxel->points
  k_scan_part<<<nb, 1024, 0, stream>>>(cnt_out, partial, Vout);
  k_scan_top<<<1, 1024, 0, stream>>>(partial, nb);
  k_scan_write<<<nb, 1024, 0, stream>>>(cnt_out, partial, starts, cursor, Vout);
  k_bucket<<<CDIV(N, 256), 256, 0, stream>>>(p2v_out, cursor, plist, N);

  // weight prep for both convs
  k_wprep<<<CDIV(27 * 2 * 4 * 64, 256), 256, 0, stream>>>(Wr1, Wh1, Wl1, 27);
  k_wprep<<<CDIV(27 * 2 * 4 * 64, 256), 256, 0, stream>>>(Wr2, Wh2, Wl2, 27);

  // fused tri1 + seg_mean -> pfeat, vf2
  k_tri1v<<<CDIV(Vout, 4), 256, 0, stream>>>(c1, sb, tri_idx, twt, starts, cnt_out,
                                             plist, pfeat, vf2, Vout);

  // pmm raw + stats (pfeat dead afterwards)
  k_pmm<<<CDIV(N, 128), 256, 0, stream>>>(pfeat, Wpt, bpt, pf2, stats + 384, N);
  k_bnfin<<<1, 64, 0, stream>>>(stats + 384, gp, bp, sb + 384, N);

  // conv block 1
  k_split<<<CDIV(Vout * 64, 256), 256, 0, stream>>>(vf2, nullptr, vf2p, Vout * 64);
  k_conv27r<<<CDIV(Vout, 128), 256, 0, stream>>>(vf2p, nbr27, Wh1, Wl1, h1,
                                                 stats + 128, Vout);
  k_bnfin<<<1, 64, 0, stream>>>(stats + 128, gr1, br1, sb + 128, Vout);

  // conv block 2
  k_split<<<CDIV(Vout * 64, 256), 256, 0, stream>>>(h1, sb + 128, h1p, Vout * 64);
  k_conv27r<<<CDIV(Vout, 128), 256, 0, stream>>>(h1p, nbr27, Wh2, Wl2, h2,
                                                 stats + 256, Vout);
  k_bnfin<<<1, 64, 0, stream>>>(stats + 256, gr2, br2, sb + 256, Vout);

  k_vf3<<<CDIV(Vout * 64, 256), 256, 0, stream>>>(h2, vf2, sb + 256, vf3, Vout * 64);

  // fused tri2 + final seg_mean -> pf2, vf4
  k_tri2v<<<CDIV(Vout, 4), 256, 0, stream>>>(vf3, sb + 384, tri_idx, twt, starts,
                                             cnt_out, plist, pf2, vf4, Vout);
}